// Round 5
// baseline (123.925 us; speedup 1.0000x reference)
//
#include <hip/hip_runtime.h>

// Fused NCA step: perception(4 fixed 3x3, wrap) -> 1x1 conv 32->16 +b+ReLU
// -> 1x1 conv 16->8 -> x + y*mask.  fp32, v_pk_fma_f32 (2 px/instr).
// R5: R4 (2px/thread, no spills, occ 81%) was latency-bound: compiler chose
// 32 VGPRs -> no load hoisting -> 8x (9 loads -> vmcnt(0) -> compute) serial
// chains. Now: hand-unrolled 2-deep channel pipeline with NAMED register
// double buffers (R3's scheme at R4's footprint: ~85 VGPR < 128 cap).

constexpr int B = 16, C = 8, H = 512, W = 512, HID = 16;
constexpr int HW = H * W;

// acc += w * p   (w uniform SGPR pair {w,w}, p/acc per-lane float2)
#define PKFMA_S(acc, w, p) \
    asm("v_pk_fma_f32 %0, %1, %2, %0" : "+v"(acc) : "s"(w), "v"(p))
// acc += a * b   (all VGPR)
#define PKFMA_V(acc, a, b) \
    asm("v_pk_fma_f32 %0, %1, %2, %0" : "+v"(acc) : "v"(a), "v"(b))

__global__ void repack_weights(const float* __restrict__ w1w,
                               const float* __restrict__ w2w,
                               float2* __restrict__ wd) {
    const int i = blockIdx.x * 256 + threadIdx.x;
    if (i < 512) {               // w1d[c][h][f] = dup(w1w[h][c*4+f])
        const int c = i >> 6, r = i & 63, h = r >> 2, f = r & 3;
        const float v = w1w[h * 32 + c * 4 + f];
        wd[i] = make_float2(v, v);
    } else if (i < 640) {        // w2d[o][h] = dup(w2w[o][h])
        const float v = w2w[i - 512];
        wd[i] = make_float2(v, v);
    }
}

__global__ __launch_bounds__(256, 4) void nca_step_kernel(
    const float* __restrict__ x,
    const float* __restrict__ w1b,
    const int*   __restrict__ mask,
    float*       __restrict__ out,
    const float2* __restrict__ wd)
{
    // block = one image row; XCD-bijective swizzle (8192 = 8 * 1024)
    const int bid = blockIdx.x;
    const int l   = (bid & 7) * 1024 + (bid >> 3);
    const int b   = l >> 9;
    const int y   = l & (H - 1);

    const int tx = threadIdx.x;
    const int x0 = tx << 1;                  // 2 px/thread
    const int xl = (x0 - 1) & (W - 1);
    const int xr = (x0 + 2) & (W - 1);
    const int ym = (y - 1) & (H - 1);
    const int yp = (y + 1) & (H - 1);

    const float* xb = x + (size_t)b * C * HW;
    const int o_m = ym * W, o_cr = y * W, o_p = yp * W;
    const int pix = o_cr + x0;

    // early loads: mask + first residual channel ride under the c-loop
    const int2 m2 = *(const int2*)(mask + (size_t)b * HW + pix);

    float2 acc[HID];                         // 32 VGPRs, static idx
#pragma unroll
    for (int h = 0; h < HID; ++h) {
        const float bv = w1b[h];             // uniform -> s_load
        acc[h] = make_float2(bv, bv);
    }

    // ---- named 2-deep double-buffer registers (NO arrays, NO lambdas) ----
    float2 Am, Ac, Ap, Bm, Bc, Bp;
    float  Al0, Al1, Al2, Ar0, Ar1, Ar2;
    float  Bl0, Bl1, Bl2, Br0, Br1, Br2;

#define LOADCH(P, ch) do {                                              \
    const float* xc_ = xb + (ch) * HW;                                  \
    P##m  = *(const float2*)(xc_ + o_m  + x0);                          \
    P##c  = *(const float2*)(xc_ + o_cr + x0);                          \
    P##p  = *(const float2*)(xc_ + o_p  + x0);                          \
    P##l0 = xc_[o_m  + xl]; P##r0 = xc_[o_m  + xr];                     \
    P##l1 = xc_[o_cr + xl]; P##r1 = xc_[o_cr + xr];                     \
    P##l2 = xc_[o_p  + xl]; P##r2 = xc_[o_p  + xr]; } while (0)

#define COMPCH(P, ch) do {                                              \
    const float cm[4] = {P##l0, P##m.x, P##m.y, P##r0};                 \
    const float cc[4] = {P##l1, P##c.x, P##c.y, P##r1};                 \
    const float cp[4] = {P##l2, P##p.x, P##p.y, P##r2};                 \
    float s_[4], d_[4];                                                 \
    _Pragma("unroll") for (int i = 0; i < 4; ++i) {                     \
        s_[i] = fmaf(2.0f, cc[i], cm[i] + cp[i]);                       \
        d_[i] = cp[i] - cm[i]; }                                        \
    const float sx0  = (s_[2] - s_[0]) * 0.125f;                        \
    const float sx1  = (s_[3] - s_[1]) * 0.125f;                        \
    const float sy0  = fmaf(2.0f, d_[1], d_[0] + d_[2]) * 0.125f;       \
    const float sy1  = fmaf(2.0f, d_[2], d_[1] + d_[3]) * 0.125f;       \
    const float lap0 = fmaf(fmaf(2.0f, s_[1], s_[0] + s_[2]), 0.0625f, -cc[1]); \
    const float lap1 = fmaf(fmaf(2.0f, s_[2], s_[1] + s_[3]), 0.0625f, -cc[2]); \
    const float2 idn2 = make_float2(cc[1], cc[2]);                      \
    const float2 sx2  = make_float2(sx0, sx1);                          \
    const float2 sy2  = make_float2(sy0, sy1);                          \
    const float2 lp2  = make_float2(lap0, lap1);                        \
    const float2* wch = wd + (ch) * 64;                                 \
    _Pragma("unroll") for (int h = 0; h < HID; ++h) {                   \
        PKFMA_S(acc[h], wch[h * 4 + 0], idn2);                          \
        PKFMA_S(acc[h], wch[h * 4 + 1], sx2);                           \
        PKFMA_S(acc[h], wch[h * 4 + 2], sy2);                           \
        PKFMA_S(acc[h], wch[h * 4 + 3], lp2); } } while (0)

    // hand-unrolled pipeline: next channel's 9 loads fly under current compute
    LOADCH(A, 0);
    LOADCH(B, 1); COMPCH(A, 0);
    LOADCH(A, 2); COMPCH(B, 1);
    LOADCH(B, 3); COMPCH(A, 2);
    LOADCH(A, 4); COMPCH(B, 3);
    LOADCH(B, 5); COMPCH(A, 4);
    LOADCH(A, 6); COMPCH(B, 5);
    LOADCH(B, 7); COMPCH(A, 6);
    COMPCH(B, 7);

#undef LOADCH
#undef COMPCH

    // ReLU
#pragma unroll
    for (int h = 0; h < HID; ++h) {
        acc[h].x = fmaxf(acc[h].x, 0.0f);
        acc[h].y = fmaxf(acc[h].y, 0.0f);
    }

    const float2 mf = make_float2((float)m2.x, (float)m2.y);
    const float2* w2d = wd + 512;
    float* ob = out + (size_t)b * C * HW;

    // epilogue: pipelined residual loads (prefetch o+1 under o's 16 pk_fma)
    float2 xo = *(const float2*)(xb + pix);
#pragma unroll
    for (int o = 0; o < C; ++o) {
        float2 xn;
        if (o + 1 < C) xn = *(const float2*)(xb + (o + 1) * HW + pix);
        float2 v = make_float2(0.0f, 0.0f);
#pragma unroll
        for (int h = 0; h < HID; ++h)
            PKFMA_S(v, w2d[o * 16 + h], acc[h]);
        PKFMA_V(xo, v, mf);                   // xo += v * mask
        *(float2*)(ob + o * HW + pix) = xo;
        xo = xn;
    }
}

extern "C" void kernel_launch(void* const* d_in, const int* in_sizes, int n_in,
                              void* d_out, int out_size, void* d_ws, size_t ws_size,
                              hipStream_t stream) {
    const float* x    = (const float*)d_in[0];
    const float* w1w  = (const float*)d_in[1];
    const float* w1b  = (const float*)d_in[2];
    const float* w2w  = (const float*)d_in[3];
    const int*   mask = (const int*)d_in[4];
    float* out = (float*)d_out;
    float2* wd = (float2*)d_ws;              // 640 * 8 B = 5 KiB scratch

    hipLaunchKernelGGL(repack_weights, dim3(3), dim3(256), 0, stream,
                       w1w, w2w, wd);
    hipLaunchKernelGGL(nca_step_kernel, dim3(B * H), dim3(256), 0, stream,
                       x, w1b, mask, out, wd);
}

// Round 6
// 96.074 us; speedup vs baseline: 1.2899x; 1.2899x over previous
//
#include <hip/hip_runtime.h>
#include <stdint.h>

// Fused NCA step: perception(4 fixed 3x3, wrap) -> 1x1 conv 32->16 +b+ReLU
// -> 1x1 conv 16->8 -> x + y*mask.  fp32, v_pk_fma_f32 (2 px/instr).
// R6: R1..R5 all latency-bound (VALUBusy<=37%, HBM<=20%): the compiler sinks
// source-level register prefetch (R2/R3 spilled, R5 got rescheduled away).
// Structural fix = T3-minimum 2-phase LDS pipeline: async global_load_lds
// (width 16) stages channel c+1's 3 rows into LDS while channel c computes
// from LDS; one __syncthreads per channel drains it. Compiler cannot defeat
// this. 12 KB LDS, 2 px/thread, pk_fma convs with SGPR {w,w} weight pairs.

constexpr int B = 16, C = 8, H = 512, W = 512, HID = 16;
constexpr int HW = H * W;
constexpr int BUF = 3 * W;   // floats per channel buffer (3 rows)

// acc += w * p   (w uniform SGPR pair {w,w}, p/acc per-lane float2)
#define PKFMA_S(acc, w, p) \
    asm("v_pk_fma_f32 %0, %1, %2, %0" : "+v"(acc) : "s"(w), "v"(p))
// acc += a * b   (all VGPR)
#define PKFMA_V(acc, a, b) \
    asm("v_pk_fma_f32 %0, %1, %2, %0" : "+v"(acc) : "v"(a), "v"(b))

typedef const __attribute__((address_space(1))) void* as1cp;
typedef __attribute__((address_space(3))) void* as3p;

__global__ void repack_weights(const float* __restrict__ w1w,
                               const float* __restrict__ w2w,
                               float2* __restrict__ wd) {
    const int i = blockIdx.x * 256 + threadIdx.x;
    if (i < 512) {               // w1d[c][h][f] = dup(w1w[h][c*4+f])
        const int c = i >> 6, r = i & 63, h = r >> 2, f = r & 3;
        const float v = w1w[h * 32 + c * 4 + f];
        wd[i] = make_float2(v, v);
    } else if (i < 640) {        // w2d[o][h] = dup(w2w[o][h])
        const float v = w2w[i - 512];
        wd[i] = make_float2(v, v);
    }
}

__global__ __launch_bounds__(256, 6) void nca_step_kernel(
    const float* __restrict__ x,
    const float* __restrict__ w1b,
    const int*   __restrict__ mask,
    float*       __restrict__ out,
    const float2* __restrict__ wd)
{
    __shared__ float S[2 * BUF];             // 12 KB: double-buffered 3-row tile

    // block = one image row; XCD-bijective swizzle (8192 = 8 * 1024)
    const int bid = blockIdx.x;
    const int l   = (bid & 7) * 1024 + (bid >> 3);
    const int b   = l >> 9;
    const int y   = l & (H - 1);

    const int tx   = threadIdx.x;
    const int x0   = tx << 1;                // 2 px/thread
    const int lane = tx & 63;
    const int wv   = tx >> 6;                // wave id 0..3 (uniform)

    const int ym = (y - 1) & (H - 1);
    const int yp = (y + 1) & (H - 1);
    const int xm1 = (x0 - 1) & (W - 1);
    const int xp2 = (x0 + 2) & (W - 1);

    const float* xb = x + (size_t)b * C * HW;
    const int pix = y * W + x0;

    // Stage geometry: 6 chunks of 1024 B (64 lanes x 16 B) cover 3 rows.
    // Issue 1: waves {0,1}->row ym halves {0,1}, waves {2,3}->row y halves.
    // Issue 2 (waves 0,1 only): row yp halves {0,1}.  All wave-uniform.
    const int hh = wv & 1;                         // 256-float half of a row
    const int g1 = ((wv < 2) ? ym : y) * W + hh * 256 + lane * 4;
    const int l1 = ((wv < 2) ? 0 : W) + hh * 256;  // LDS float offset (uniform)
    const int g2 = yp * W + hh * 256 + lane * 4;
    const int l2 = 2 * W + hh * 256;

#define STAGE(ch, bufo) do {                                               \
    const float* cb_ = xb + (ch) * HW;                                     \
    __builtin_amdgcn_global_load_lds((as1cp)(cb_ + g1),                    \
                                     (as3p)(S + (bufo) + l1), 16, 0, 0);   \
    if (wv < 2)                                                            \
        __builtin_amdgcn_global_load_lds((as1cp)(cb_ + g2),                \
                                         (as3p)(S + (bufo) + l2), 16, 0, 0); \
    } while (0)

#define COMPCH(ch, bufo) do {                                              \
    const float* R0 = S + (bufo);                                          \
    const float* R1 = R0 + W;                                              \
    const float* R2 = R1 + W;                                              \
    const float2 vm = *(const float2*)(R0 + x0);                           \
    const float2 vc = *(const float2*)(R1 + x0);                           \
    const float2 vp = *(const float2*)(R2 + x0);                           \
    const float cm[4] = {R0[xm1], vm.x, vm.y, R0[xp2]};                    \
    const float cc[4] = {R1[xm1], vc.x, vc.y, R1[xp2]};                    \
    const float cp[4] = {R2[xm1], vp.x, vp.y, R2[xp2]};                    \
    float s_[4], d_[4];                                                    \
    _Pragma("unroll") for (int i = 0; i < 4; ++i) {                        \
        s_[i] = fmaf(2.0f, cc[i], cm[i] + cp[i]);                          \
        d_[i] = cp[i] - cm[i]; }                                           \
    const float sx0  = (s_[2] - s_[0]) * 0.125f;                           \
    const float sx1  = (s_[3] - s_[1]) * 0.125f;                           \
    const float sy0  = fmaf(2.0f, d_[1], d_[0] + d_[2]) * 0.125f;          \
    const float sy1  = fmaf(2.0f, d_[2], d_[1] + d_[3]) * 0.125f;          \
    const float lap0 = fmaf(fmaf(2.0f, s_[1], s_[0] + s_[2]), 0.0625f, -cc[1]); \
    const float lap1 = fmaf(fmaf(2.0f, s_[2], s_[1] + s_[3]), 0.0625f, -cc[2]); \
    const float2 idn2 = make_float2(cc[1], cc[2]);                         \
    const float2 sx2  = make_float2(sx0, sx1);                             \
    const float2 sy2  = make_float2(sy0, sy1);                             \
    const float2 lp2  = make_float2(lap0, lap1);                           \
    const float2* wch = wd + (ch) * 64;                                    \
    _Pragma("unroll") for (int h = 0; h < HID; ++h) {                      \
        PKFMA_S(acc[h], wch[h * 4 + 0], idn2);                             \
        PKFMA_S(acc[h], wch[h * 4 + 1], sx2);                              \
        PKFMA_S(acc[h], wch[h * 4 + 2], sy2);                              \
        PKFMA_S(acc[h], wch[h * 4 + 3], lp2); } } while (0)

    // mask early; latency hidden under the first channel phases
    const int2 m2 = *(const int2*)(mask + (size_t)b * HW + pix);

    float2 acc[HID];                         // 32 VGPRs, static idx (unrolled)
#pragma unroll
    for (int h = 0; h < HID; ++h) {
        const float bv = w1b[h];             // uniform -> s_load
        acc[h] = make_float2(bv, bv);
    }

    // ---- 2-phase channel pipeline: stage c+1 async, compute c from LDS ----
    STAGE(0, 0);
    __syncthreads();                         // vmcnt(0)+lgkmcnt(0)+barrier
    STAGE(1, BUF); COMPCH(0, 0);   __syncthreads();
    STAGE(2, 0);   COMPCH(1, BUF); __syncthreads();
    STAGE(3, BUF); COMPCH(2, 0);   __syncthreads();
    STAGE(4, 0);   COMPCH(3, BUF); __syncthreads();
    STAGE(5, BUF); COMPCH(4, 0);   __syncthreads();
    STAGE(6, 0);   COMPCH(5, BUF); __syncthreads();
    STAGE(7, BUF); COMPCH(6, 0);   __syncthreads();
                   COMPCH(7, BUF);

#undef STAGE
#undef COMPCH

    // ReLU
#pragma unroll
    for (int h = 0; h < HID; ++h) {
        acc[h].x = fmaxf(acc[h].x, 0.0f);
        acc[h].y = fmaxf(acc[h].y, 0.0f);
    }

    const float2 mf = make_float2((float)m2.x, (float)m2.y);
    const float2* w2d = wd + 512;
    float* ob = out + (size_t)b * C * HW;

    // epilogue: pipelined residual loads (prefetch o+1 under o's 16 pk_fma)
    float2 xo = *(const float2*)(xb + pix);
#pragma unroll
    for (int o = 0; o < C; ++o) {
        float2 xn;
        if (o + 1 < C) xn = *(const float2*)(xb + (o + 1) * HW + pix);
        float2 v = make_float2(0.0f, 0.0f);
#pragma unroll
        for (int h = 0; h < HID; ++h)
            PKFMA_S(v, w2d[o * 16 + h], acc[h]);
        PKFMA_V(xo, v, mf);                   // xo += v * mask
        *(float2*)(ob + o * HW + pix) = xo;
        xo = xn;
    }
}

extern "C" void kernel_launch(void* const* d_in, const int* in_sizes, int n_in,
                              void* d_out, int out_size, void* d_ws, size_t ws_size,
                              hipStream_t stream) {
    const float* x    = (const float*)d_in[0];
    const float* w1w  = (const float*)d_in[1];
    const float* w1b  = (const float*)d_in[2];
    const float* w2w  = (const float*)d_in[3];
    const int*   mask = (const int*)d_in[4];
    float* out = (float*)d_out;
    float2* wd = (float2*)d_ws;              // 640 * 8 B = 5 KiB scratch

    hipLaunchKernelGGL(repack_weights, dim3(3), dim3(256), 0, stream,
                       w1w, w2w, wd);
    hipLaunchKernelGGL(nca_step_kernel, dim3(B * H), dim3(256), 0, stream,
                       x, w1b, mask, out, wd);
}